// Round 1
// baseline (580.593 us; speedup 1.0000x reference)
//
#include <hip/hip_runtime.h>
#include <hip/hip_bf16.h>
#include <stdint.h>

typedef __bf16 bf16x8 __attribute__((ext_vector_type(8)));
typedef float f32x4 __attribute__((ext_vector_type(4)));
typedef __hip_bfloat16 bf16;

// Problem constants
#define D_MODEL 1024
#define BATCH 4
#define NSEQ 4096
#define RATIO 4
#define NTOK (BATCH * NSEQ)            // 16384 rows for Q / final GEMM
#define MTOK (BATCH * (NSEQ / RATIO))  // 4096 rows for K/V GEMM

// ---------------- async global->LDS (16B per lane) ----------------
__device__ __forceinline__ void async_copy16(const void* g, void* l) {
  __builtin_amdgcn_global_load_lds(
      (const __attribute__((address_space(1))) void*)g,
      (__attribute__((address_space(3))) void*)l, 16, 0, 0);
}

__device__ __forceinline__ float to_f32(float v) { return v; }
__device__ __forceinline__ float to_f32(bf16 v) { return __bfloat162float(v); }

// ---------------- LayerNorm: fp32 in -> bf16 out ----------------
__global__ __launch_bounds__(256) void ln_kernel(
    const float* __restrict__ x, const float* __restrict__ g,
    const float* __restrict__ b, bf16* __restrict__ xn) {
  const size_t row = blockIdx.x;
  const float4* xr = (const float4*)(x + row * D_MODEL);
  const int tid = threadIdx.x;
  float4 v = xr[tid];
  float s = v.x + v.y + v.z + v.w;
  float sq = v.x * v.x + v.y * v.y + v.z * v.z + v.w * v.w;
#pragma unroll
  for (int o = 1; o < 64; o <<= 1) {
    s += __shfl_xor(s, o);
    sq += __shfl_xor(sq, o);
  }
  __shared__ float rs[4], rq[4];
  if ((tid & 63) == 0) { rs[tid >> 6] = s; rq[tid >> 6] = sq; }
  __syncthreads();
  s = rs[0] + rs[1] + rs[2] + rs[3];
  sq = rq[0] + rq[1] + rq[2] + rq[3];
  const float mu = s * (1.f / D_MODEL);
  const float var = sq * (1.f / D_MODEL) - mu * mu;
  const float rstd = rsqrtf(var + 1e-5f);
  float4 gv = ((const float4*)g)[tid];
  float4 bv = ((const float4*)b)[tid];
  union { ushort4 u; bf16 h[4]; } pk;
  pk.h[0] = __float2bfloat16((v.x - mu) * rstd * gv.x + bv.x);
  pk.h[1] = __float2bfloat16((v.y - mu) * rstd * gv.y + bv.y);
  pk.h[2] = __float2bfloat16((v.z - mu) * rstd * gv.z + bv.z);
  pk.h[3] = __float2bfloat16((v.w - mu) * rstd * gv.w + bv.w);
  ((ushort4*)(xn + row * D_MODEL))[tid] = pk.u;
}

// ---------------- transpose (R,C) -> (C,R), output bf16 ----------------
template <typename T>
__global__ __launch_bounds__(256) void transpose_to_bf16(
    const T* __restrict__ in, bf16* __restrict__ out, int R, int C) {
  __shared__ bf16 tile[32][33];
  const int tx = threadIdx.x;  // 0..31
  const int ty = threadIdx.y;  // 0..7
  const int c0 = blockIdx.x * 32;
  const int r0 = blockIdx.y * 32;
  const size_t base = (size_t)blockIdx.z * (size_t)R * C;
#pragma unroll
  for (int i = 0; i < 4; i++) {
    const int r = r0 + ty + i * 8;
    tile[ty + i * 8][tx] = __float2bfloat16(to_f32(in[base + (size_t)r * C + c0 + tx]));
  }
  __syncthreads();
#pragma unroll
  for (int i = 0; i < 4; i++) {
    const int oc = c0 + ty + i * 8;  // output row (= input col)
    out[base + (size_t)oc * R + r0 + tx] = tile[tx][ty + i * 8];
  }
}

// ---------------- GEMM: C = scale*(A @ Bt^T) + bias ----------------
// A: (M,K) bf16 row-major.  Bt: (N,K) bf16 row-major (i.e. B^T).
// C: (M,N) CT.  batched via blockIdx.z strides.
// 128x128 tile, 4 waves (2x2 of 64x64), BK=64, mfma_f32_16x16x32_bf16.
template <typename CT, bool HAS_BIAS>
__global__ __launch_bounds__(256) void gemm_bt(
    const bf16* __restrict__ A, const bf16* __restrict__ Bt,
    CT* __restrict__ C, const float* __restrict__ bias, float scale,
    int M, int N, int K, size_t aStride, size_t bStride, size_t cStride) {
  __shared__ __align__(16) bf16 As[128 * 64];
  __shared__ __align__(16) bf16 Bs[128 * 64];
  const int tid = threadIdx.x;
  const int lane = tid & 63;
  const int wid = tid >> 6;
  const int wr = wid >> 1, wc = wid & 1;
  const int bn0 = blockIdx.x * 128;
  const int bm0 = blockIdx.y * 128;
  A += (size_t)blockIdx.z * aStride;
  Bt += (size_t)blockIdx.z * bStride;
  C += (size_t)blockIdx.z * cStride;

  f32x4 acc[4][4] = {};

  // staging: 256 threads x 16B x 4 issues = 16KB = 128 rows x 64 bf16
  const int srow = tid >> 3;       // 0..31
  const int scol = (tid & 7) * 8;  // bf16 col within the 64-wide K slab
  const bf16* aPtr = A + (size_t)(bm0 + srow) * K + scol;
  const bf16* bPtr = Bt + (size_t)(bn0 + srow) * K + scol;
  char* aLds = (char*)As + tid * 16;
  char* bLds = (char*)Bs + tid * 16;

  // fragment read offsets (A: row=lane&15, k=(lane>>4)*8 ; B: col=lane&15)
  const int a_off = (wr * 64 + (lane & 15)) * 64 + (lane >> 4) * 8;
  const int b_off = (wc * 64 + (lane & 15)) * 64 + (lane >> 4) * 8;

  for (int k0 = 0; k0 < K; k0 += 64) {
#pragma unroll
    for (int i = 0; i < 4; i++) {
      async_copy16(aPtr + (size_t)(i * 32) * K + k0, aLds + i * 4096);
      async_copy16(bPtr + (size_t)(i * 32) * K + k0, bLds + i * 4096);
    }
    __syncthreads();  // drains vmcnt before barrier -> LDS ready
#pragma unroll
    for (int kk = 0; kk < 64; kk += 32) {
      bf16x8 af[4], bfv[4];
#pragma unroll
      for (int m = 0; m < 4; m++)
        af[m] = *reinterpret_cast<const bf16x8*>(&As[a_off + m * 16 * 64 + kk]);
#pragma unroll
      for (int n = 0; n < 4; n++)
        bfv[n] = *reinterpret_cast<const bf16x8*>(&Bs[b_off + n * 16 * 64 + kk]);
#pragma unroll
      for (int m = 0; m < 4; m++)
#pragma unroll
        for (int n = 0; n < 4; n++)
          acc[m][n] = __builtin_amdgcn_mfma_f32_16x16x32_bf16(af[m], bfv[n], acc[m][n], 0, 0, 0);
    }
    __syncthreads();
  }

  // epilogue: C/D layout col=lane&15, row=(lane>>4)*4+j
  const int cl = lane & 15;
  const int rg = lane >> 4;
#pragma unroll
  for (int m = 0; m < 4; m++) {
#pragma unroll
    for (int n = 0; n < 4; n++) {
      const int col = bn0 + wc * 64 + n * 16 + cl;
      float bv = HAS_BIAS ? bias[col] : 0.f;
#pragma unroll
      for (int j = 0; j < 4; j++) {
        const int row = bm0 + wr * 64 + m * 16 + rg * 4 + j;
        const float v = acc[m][n][j] * scale + bv;
        if constexpr (sizeof(CT) == 2)
          C[(size_t)row * N + col] = __float2bfloat16(v);
        else
          C[(size_t)row * N + col] = v;
      }
    }
  }
}

// ---------------- row softmax: fp32 scores -> bf16 probs ----------------
__global__ __launch_bounds__(256) void softmax_kernel(
    const float* __restrict__ S, bf16* __restrict__ P) {
  const size_t row = blockIdx.x;
  const float4* sp = (const float4*)(S + row * 1024);
  const int tid = threadIdx.x;
  float4 v = sp[tid];
  float mx = fmaxf(fmaxf(v.x, v.y), fmaxf(v.z, v.w));
#pragma unroll
  for (int o = 1; o < 64; o <<= 1) mx = fmaxf(mx, __shfl_xor(mx, o));
  __shared__ float red[4];
  __shared__ float red2[4];
  if ((tid & 63) == 0) red[tid >> 6] = mx;
  __syncthreads();
  mx = fmaxf(fmaxf(red[0], red[1]), fmaxf(red[2], red[3]));
  const float e0 = __expf(v.x - mx), e1 = __expf(v.y - mx);
  const float e2 = __expf(v.z - mx), e3 = __expf(v.w - mx);
  float s = e0 + e1 + e2 + e3;
#pragma unroll
  for (int o = 1; o < 64; o <<= 1) s += __shfl_xor(s, o);
  if ((tid & 63) == 0) red2[tid >> 6] = s;
  __syncthreads();
  s = red2[0] + red2[1] + red2[2] + red2[3];
  const float inv = 1.f / s;
  union { ushort4 u; bf16 h[4]; } pk;
  pk.h[0] = __float2bfloat16(e0 * inv);
  pk.h[1] = __float2bfloat16(e1 * inv);
  pk.h[2] = __float2bfloat16(e2 * inv);
  pk.h[3] = __float2bfloat16(e3 * inv);
  ((ushort4*)(P + row * 1024))[tid] = pk.u;
}

extern "C" void kernel_launch(void* const* d_in, const int* in_sizes, int n_in,
                              void* d_out, int out_size, void* d_ws, size_t ws_size,
                              hipStream_t stream) {
  const float* x = (const float*)d_in[0];
  const float* ln_g = (const float*)d_in[1];
  const float* ln_b = (const float*)d_in[2];
  const float* Wq = (const float*)d_in[3];
  const float* bq = (const float*)d_in[4];
  const float* Wk = (const float*)d_in[5];
  const float* bk = (const float*)d_in[6];
  const float* Wv = (const float*)d_in[7];
  const float* bv = (const float*)d_in[8];
  const float* Wo = (const float*)d_in[9];
  const float* bo = (const float*)d_in[10];
  float* out = (float*)d_out;

  // workspace layout (all 256B aligned)
  char* w = (char*)d_ws;
  auto alloc = [&](size_t bytes) {
    char* p = w;
    w += (bytes + 255) & ~(size_t)255;
    return p;
  };
  bf16* xn    = (bf16*)alloc((size_t)NTOK * D_MODEL * 2);        // 32MB
  bf16* WqT   = (bf16*)alloc((size_t)D_MODEL * D_MODEL * 2);     // 2MB
  bf16* WkT   = (bf16*)alloc((size_t)D_MODEL * 4 * D_MODEL * 2); // 8MB
  bf16* WvT   = (bf16*)alloc((size_t)D_MODEL * 4 * D_MODEL * 2); // 8MB
  bf16* WoT   = (bf16*)alloc((size_t)D_MODEL * D_MODEL * 2);     // 2MB
  bf16* q     = (bf16*)alloc((size_t)NTOK * D_MODEL * 2);        // 32MB (reused as attn_out)
  bf16* kbuf  = (bf16*)alloc((size_t)MTOK * D_MODEL * 2);        // 8MB
  bf16* vbuf  = (bf16*)alloc((size_t)MTOK * D_MODEL * 2);        // 8MB
  bf16* vT    = (bf16*)alloc((size_t)MTOK * D_MODEL * 2);        // 8MB
  float* sc   = (float*)alloc((size_t)NTOK * 1024 * 4);          // 64MB scores
  bf16* attn  = (bf16*)alloc((size_t)NTOK * 1024 * 2);           // 32MB
  bf16* aout  = q;  // q is dead after the scores GEMM

  // 1) LayerNorm -> bf16
  ln_kernel<<<NTOK, 256, 0, stream>>>(x, ln_g, ln_b, xn);

  // 2) weight convert+transpose to (N,K) bf16
  transpose_to_bf16<float><<<dim3(32, 32, 1), dim3(32, 8), 0, stream>>>(Wq, WqT, 1024, 1024);
  transpose_to_bf16<float><<<dim3(32, 128, 1), dim3(32, 8), 0, stream>>>(Wk, WkT, 4096, 1024);
  transpose_to_bf16<float><<<dim3(32, 128, 1), dim3(32, 8), 0, stream>>>(Wv, WvT, 4096, 1024);
  transpose_to_bf16<float><<<dim3(32, 32, 1), dim3(32, 8), 0, stream>>>(Wo, WoT, 1024, 1024);

  // 3) Q = xn @ Wq + bq           (16384,1024,K=1024) -> bf16
  gemm_bt<bf16, true><<<dim3(8, 128, 1), 256, 0, stream>>>(
      xn, WqT, q, bq, 1.f, NTOK, 1024, 1024, 0, 0, 0);
  // 4) K = xr @ Wk + bk           (4096,1024,K=4096) -> bf16
  gemm_bt<bf16, true><<<dim3(8, 32, 1), 256, 0, stream>>>(
      xn, WkT, kbuf, bk, 1.f, MTOK, 1024, 4096, 0, 0, 0);
  // 5) V = xr @ Wv + bv
  gemm_bt<bf16, true><<<dim3(8, 32, 1), 256, 0, stream>>>(
      xn, WvT, vbuf, bv, 1.f, MTOK, 1024, 4096, 0, 0, 0);

  // 6) vT for the PV GEMM (per-batch 1024x1024 transpose)
  transpose_to_bf16<bf16><<<dim3(32, 32, BATCH), dim3(32, 8), 0, stream>>>(vbuf, vT, 1024, 1024);

  // 7) scores = (q @ k^T) / 32    batched, fp32 out
  gemm_bt<float, false><<<dim3(8, 32, BATCH), 256, 0, stream>>>(
      q, kbuf, sc, nullptr, 0.03125f, NSEQ, 1024, 1024,
      (size_t)NSEQ * 1024, (size_t)1024 * 1024, (size_t)NSEQ * 1024);

  // 8) softmax rows -> bf16
  softmax_kernel<<<NTOK, 256, 0, stream>>>(sc, attn);

  // 9) attn @ v                   batched, bf16 out (into q's buffer)
  gemm_bt<bf16, false><<<dim3(8, 32, BATCH), 256, 0, stream>>>(
      attn, vT, aout, nullptr, 1.f, NSEQ, 1024, 1024,
      (size_t)NSEQ * 1024, (size_t)1024 * 1024, (size_t)NSEQ * 1024);

  // 10) out = aout @ Wo + bo      fp32 to d_out
  gemm_bt<float, true><<<dim3(8, 128, 1), 256, 0, stream>>>(
      aout, WoT, out, bo, 1.f, NTOK, 1024, 1024, 0, 0, 0);
}

// Round 2
// 473.709 us; speedup vs baseline: 1.2256x; 1.2256x over previous
//
#include <hip/hip_runtime.h>
#include <hip/hip_bf16.h>
#include <stdint.h>

typedef __bf16 bf16x8 __attribute__((ext_vector_type(8)));
typedef float f32x4 __attribute__((ext_vector_type(4)));
typedef __hip_bfloat16 bf16;

#define D_MODEL 1024
#define BATCH 4
#define NSEQ 4096
#define NTOK (BATCH * NSEQ)            // 16384
#define MTOK (BATCH * (NSEQ / 4))      // 4096

// ---------------- async global->LDS (16B per lane) ----------------
__device__ __forceinline__ void async_copy16(const void* g, void* l) {
  __builtin_amdgcn_global_load_lds(
      (const __attribute__((address_space(1))) void*)g,
      (__attribute__((address_space(3))) void*)l, 16, 0, 0);
}

__device__ __forceinline__ float to_f32(float v) { return v; }
__device__ __forceinline__ float to_f32(bf16 v) { return __bfloat162float(v); }

// ---------------- LayerNorm: fp32 in -> bf16 out ----------------
__global__ __launch_bounds__(256) void ln_kernel(
    const float* __restrict__ x, const float* __restrict__ g,
    const float* __restrict__ b, bf16* __restrict__ xn) {
  const size_t row = blockIdx.x;
  const float4* xr = (const float4*)(x + row * D_MODEL);
  const int tid = threadIdx.x;
  float4 v = xr[tid];
  float s = v.x + v.y + v.z + v.w;
  float sq = v.x * v.x + v.y * v.y + v.z * v.z + v.w * v.w;
#pragma unroll
  for (int o = 1; o < 64; o <<= 1) {
    s += __shfl_xor(s, o);
    sq += __shfl_xor(sq, o);
  }
  __shared__ float rs[4], rq[4];
  if ((tid & 63) == 0) { rs[tid >> 6] = s; rq[tid >> 6] = sq; }
  __syncthreads();
  s = rs[0] + rs[1] + rs[2] + rs[3];
  sq = rq[0] + rq[1] + rq[2] + rq[3];
  const float mu = s * (1.f / D_MODEL);
  const float var = sq * (1.f / D_MODEL) - mu * mu;
  const float rstd = rsqrtf(var + 1e-5f);
  float4 gv = ((const float4*)g)[tid];
  float4 bv = ((const float4*)b)[tid];
  union { ushort4 u; bf16 h[4]; } pk;
  pk.h[0] = __float2bfloat16((v.x - mu) * rstd * gv.x + bv.x);
  pk.h[1] = __float2bfloat16((v.y - mu) * rstd * gv.y + bv.y);
  pk.h[2] = __float2bfloat16((v.z - mu) * rstd * gv.z + bv.z);
  pk.h[3] = __float2bfloat16((v.w - mu) * rstd * gv.w + bv.w);
  ((ushort4*)(xn + row * D_MODEL))[tid] = pk.u;
}

// ---------------- transpose (R,C)@ldin -> (C,R)@ldout, bf16 out ----------------
template <typename T>
__global__ __launch_bounds__(256) void transpose_to_bf16(
    const T* __restrict__ in, bf16* __restrict__ out, int ldin, int ldout,
    size_t inStride, size_t outStride) {
  __shared__ bf16 tile[32][33];
  const int tx = threadIdx.x;  // 0..31
  const int ty = threadIdx.y;  // 0..7
  const int c0 = blockIdx.x * 32;
  const int r0 = blockIdx.y * 32;
  const T* ip = in + (size_t)blockIdx.z * inStride;
  bf16* op = out + (size_t)blockIdx.z * outStride;
#pragma unroll
  for (int i = 0; i < 4; i++) {
    const int r = r0 + ty + i * 8;
    tile[ty + i * 8][tx] = __float2bfloat16(to_f32(ip[(size_t)r * ldin + c0 + tx]));
  }
  __syncthreads();
#pragma unroll
  for (int i = 0; i < 4; i++) {
    const int oc = c0 + ty + i * 8;
    op[(size_t)oc * ldout + r0 + tx] = tile[tx][ty + i * 8];
  }
}

// ---------------- bias concat [a;b] (1024 each) ----------------
__global__ __launch_bounds__(256) void pack2(const float* __restrict__ a,
                                             const float* __restrict__ b,
                                             float* __restrict__ o) {
  const int i = blockIdx.x * 256 + threadIdx.x;
  o[i] = (i < 1024) ? a[i] : b[i - 1024];
}

// ---------------- row softmax: fp32 scores -> bf16 probs ----------------
__global__ __launch_bounds__(256) void softmax_kernel(
    const float* __restrict__ S, bf16* __restrict__ P) {
  const size_t row = blockIdx.x;
  const float4* sp = (const float4*)(S + row * 1024);
  const int tid = threadIdx.x;
  float4 v = sp[tid];
  float mx = fmaxf(fmaxf(v.x, v.y), fmaxf(v.z, v.w));
#pragma unroll
  for (int o = 1; o < 64; o <<= 1) mx = fmaxf(mx, __shfl_xor(mx, o));
  __shared__ float red[4];
  __shared__ float red2[4];
  if ((tid & 63) == 0) red[tid >> 6] = mx;
  __syncthreads();
  mx = fmaxf(fmaxf(red[0], red[1]), fmaxf(red[2], red[3]));
  const float e0 = __expf(v.x - mx), e1 = __expf(v.y - mx);
  const float e2 = __expf(v.z - mx), e3 = __expf(v.w - mx);
  float s = e0 + e1 + e2 + e3;
#pragma unroll
  for (int o = 1; o < 64; o <<= 1) s += __shfl_xor(s, o);
  if ((tid & 63) == 0) red2[tid >> 6] = s;
  __syncthreads();
  s = red2[0] + red2[1] + red2[2] + red2[3];
  const float inv = 1.f / s;
  union { ushort4 u; bf16 h[4]; } pk;
  pk.h[0] = __float2bfloat16(e0 * inv);
  pk.h[1] = __float2bfloat16(e1 * inv);
  pk.h[2] = __float2bfloat16(e2 * inv);
  pk.h[3] = __float2bfloat16(e3 * inv);
  ((ushort4*)(P + row * 1024))[tid] = pk.u;
}

// ---------------- 8-phase 256x256 GEMM: C = scale*(A @ Bt^T) + bias ----------
// A: (M,K)@lda bf16.  Bt: (N,K)@ldb bf16 (B^T).  C: (M,N)@ldc CT.
// 8 waves (2M x 4N), per-wave 128x64 out, BK=64, 2 K-tiles/iteration,
// st_16x32 LDS swizzle (linear dest + inverse-swizzled global source),
// counted vmcnt(6) at phases 4/8, setprio(1) around MFMA clusters.
template <typename CT, bool HAS_BIAS>
__global__ __launch_bounds__(512, 2) void gemm8p(
    const bf16* __restrict__ A, const bf16* __restrict__ Bt,
    CT* __restrict__ C, const float* __restrict__ bias, float scale,
    int K, int lda, int ldb, int ldc,
    size_t aStride, size_t bStride, size_t cStride) {
  __shared__ __align__(128) char lds[131072];  // 2 bufs x (A 32KB + B 32KB)
  const int tid = threadIdx.x;
  const int lane = tid & 63;
  const int wid = tid >> 6;   // 0..7
  const int wr = wid >> 2;    // 0..1  (M half)
  const int wc = wid & 3;     // 0..3  (N quarter)
  const int bn0 = blockIdx.x * 256;
  const int bm0 = blockIdx.y * 256;
  A += (size_t)blockIdx.z * aStride;
  Bt += (size_t)blockIdx.z * bStride;
  C += (size_t)blockIdx.z * cStride;

  // staging: landing slot o within a 16KB half; inverse-swizzle to logical (r,c)
  const bf16* pa[2];
  const bf16* pb[2];
  int lo[2];
#pragma unroll
  for (int j = 0; j < 2; j++) {
    const int o = tid * 16 + j * 8192;
    const int L = o ^ (((o >> 9) & 1) << 5);
    const int r = L >> 7;
    const int c = (L & 127) >> 1;
    pa[j] = A + (size_t)(bm0 + r) * lda + c;
    pb[j] = Bt + (size_t)(bn0 + r) * ldb + c;
    lo[j] = o;
  }

  // swizzled ds_read bases (swizzle bit depends only on (row>>2)&1 here)
  const int arow = wr * 128 + (lane & 15);
  const int brow = wc * 64 + (lane & 15);
  const int aRd = (arow * 128 + (lane >> 4) * 16) ^ (((arow >> 2) & 1) << 5);
  const int bRd = (brow * 128 + (lane >> 4) * 16) ^ (((brow >> 2) & 1) << 5);

  bf16x8 Af[2][4][2];  // [mh][m2][kk]
  bf16x8 Bf[2][2];     // [n2][kk] (current nh)
  f32x4 acc[8][4];
#pragma unroll
  for (int m = 0; m < 8; m++)
#pragma unroll
    for (int n = 0; n < 4; n++) acc[m][n] = (f32x4){0.f, 0.f, 0.f, 0.f};

#define STAGE_A(b, h, kt) { const size_t go = (size_t)((h) * 128) * lda + (size_t)(kt) * 64; \
  _Pragma("unroll") for (int j = 0; j < 2; j++) \
    async_copy16(pa[j] + go, lds + (b) * 65536 + (h) * 16384 + lo[j]); }
#define STAGE_B(b, h, kt) { const size_t go = (size_t)((h) * 128) * ldb + (size_t)(kt) * 64; \
  _Pragma("unroll") for (int j = 0; j < 2; j++) \
    async_copy16(pb[j] + go, lds + (b) * 65536 + 32768 + (h) * 16384 + lo[j]); }
#define READ_A(b) _Pragma("unroll") for (int mh = 0; mh < 2; mh++) \
  _Pragma("unroll") for (int m2 = 0; m2 < 4; m2++) \
  _Pragma("unroll") for (int kk = 0; kk < 2; kk++) \
    Af[mh][m2][kk] = *(const bf16x8*)(lds + (b) * 65536 + (aRd + (mh * 4 + m2) * 2048 + kk * 64));
#define READ_B(b, nh) _Pragma("unroll") for (int n2 = 0; n2 < 2; n2++) \
  _Pragma("unroll") for (int kk = 0; kk < 2; kk++) \
    Bf[n2][kk] = *(const bf16x8*)(lds + (b) * 65536 + 32768 + (bRd + ((nh) * 2 + n2) * 2048 + kk * 64));
#define MFMA_Q(MH, NH) { __builtin_amdgcn_s_setprio(1); \
  _Pragma("unroll") for (int m2 = 0; m2 < 4; m2++) \
  _Pragma("unroll") for (int n2 = 0; n2 < 2; n2++) \
  _Pragma("unroll") for (int kk = 0; kk < 2; kk++) \
    acc[(MH) * 4 + m2][(NH) * 2 + n2] = __builtin_amdgcn_mfma_f32_16x16x32_bf16( \
        Af[MH][m2][kk], Bf[n2][kk], acc[(MH) * 4 + m2][(NH) * 2 + n2], 0, 0, 0); \
  __builtin_amdgcn_s_setprio(0); }
#define BARR() { __builtin_amdgcn_sched_barrier(0); __builtin_amdgcn_s_barrier(); __builtin_amdgcn_sched_barrier(0); }
#define LGKM0() { asm volatile("s_waitcnt lgkmcnt(0)" ::: "memory"); __builtin_amdgcn_sched_barrier(0); }
#define VMC(n) { asm volatile("s_waitcnt vmcnt(" #n ")" ::: "memory"); __builtin_amdgcn_sched_barrier(0); }

  // prologue: tile0 -> buf0 (all 4 halves), tile1 -> buf1 (A0,A1,B0)
  STAGE_A(0, 0, 0) STAGE_A(0, 1, 0) STAGE_B(0, 0, 0) STAGE_B(0, 1, 0)
  STAGE_A(1, 0, 1) STAGE_A(1, 1, 1) STAGE_B(1, 0, 1)
  VMC(6)
  BARR()

  const int NIT = K >> 7;  // iterations of 2 K-tiles (BK=64 each)
  for (int it = 0; it < NIT - 1; ++it) {
    const int kt = it * 2;
    // P1: read all A + B(nh0) of tile kt; stage tile kt+1 B-h1 -> buf1
    READ_A(0) READ_B(0, 0)
    STAGE_B(1, 1, kt + 1)
    BARR()
    MFMA_Q(0, 0)
    LGKM0()          // drain unconsumed A(mh1) reads before waves cross barrier
    BARR()
    // P2
    STAGE_A(0, 0, kt + 2)
    BARR()
    MFMA_Q(1, 0)
    BARR()
    // P3
    READ_B(0, 1)
    STAGE_A(0, 1, kt + 2)
    BARR()
    MFMA_Q(0, 1)
    BARR()
    // P4
    STAGE_B(0, 0, kt + 2)
    VMC(6)           // guarantees tile kt+1 fully landed (3 half-tiles in flight)
    BARR()
    MFMA_Q(1, 1)
    BARR()
    // P5: tile kt+1 from buf1
    READ_A(1) READ_B(1, 0)
    STAGE_B(0, 1, kt + 2)
    BARR()
    MFMA_Q(0, 0)
    LGKM0()
    BARR()
    // P6
    STAGE_A(1, 0, kt + 3)
    BARR()
    MFMA_Q(1, 0)
    BARR()
    // P7
    READ_B(1, 1)
    STAGE_A(1, 1, kt + 3)
    BARR()
    MFMA_Q(0, 1)
    BARR()
    // P8
    STAGE_B(1, 0, kt + 3)
    VMC(6)           // guarantees tile kt+2 fully landed
    BARR()
    MFMA_Q(1, 1)
    BARR()
  }
  // final iteration (kt = 2*NIT-2): no further prefetch
  {
    const int kt = (NIT - 1) * 2;
    READ_A(0) READ_B(0, 0)
    STAGE_B(1, 1, kt + 1)
    BARR()
    MFMA_Q(0, 0)
    LGKM0()
    BARR()
    MFMA_Q(1, 0)
    READ_B(0, 1)
    MFMA_Q(0, 1)
    MFMA_Q(1, 1)
    VMC(0)           // tile kt+1 (incl. B-h1 staged above) fully landed
    BARR()
    READ_A(1) READ_B(1, 0)
    MFMA_Q(0, 0)
    MFMA_Q(1, 0)
    READ_B(1, 1)
    MFMA_Q(0, 1)
    MFMA_Q(1, 1)
  }
#undef STAGE_A
#undef STAGE_B
#undef READ_A
#undef READ_B
#undef MFMA_Q
#undef BARR
#undef LGKM0
#undef VMC

  // epilogue: C/D layout col=lane&15, row=(lane>>4)*4+j
  const int cl = lane & 15;
  const int rg = lane >> 4;
#pragma unroll
  for (int m = 0; m < 8; m++) {
#pragma unroll
    for (int n = 0; n < 4; n++) {
      const int col = bn0 + wc * 64 + n * 16 + cl;
      const float bv = HAS_BIAS ? bias[col] : 0.f;
#pragma unroll
      for (int j = 0; j < 4; j++) {
        const int row = bm0 + wr * 128 + m * 16 + rg * 4 + j;
        const float v = acc[m][n][j] * scale + bv;
        if constexpr (sizeof(CT) == 2)
          C[(size_t)row * ldc + col] = __float2bfloat16(v);
        else
          C[(size_t)row * ldc + col] = v;
      }
    }
  }
}

extern "C" void kernel_launch(void* const* d_in, const int* in_sizes, int n_in,
                              void* d_out, int out_size, void* d_ws, size_t ws_size,
                              hipStream_t stream) {
  const float* x = (const float*)d_in[0];
  const float* ln_g = (const float*)d_in[1];
  const float* ln_b = (const float*)d_in[2];
  const float* Wq = (const float*)d_in[3];
  const float* bq = (const float*)d_in[4];
  const float* Wk = (const float*)d_in[5];
  const float* bk = (const float*)d_in[6];
  const float* Wv = (const float*)d_in[7];
  const float* bv = (const float*)d_in[8];
  const float* Wo = (const float*)d_in[9];
  const float* bo = (const float*)d_in[10];
  float* out = (float*)d_out;

  char* w = (char*)d_ws;
  auto alloc = [&](size_t bytes) {
    char* p = w;
    w += (bytes + 255) & ~(size_t)255;
    return p;
  };
  bf16* xn    = (bf16*)alloc((size_t)NTOK * D_MODEL * 2);            // 32MB
  bf16* WqT   = (bf16*)alloc((size_t)D_MODEL * D_MODEL * 2);         // 2MB
  bf16* WkvT  = (bf16*)alloc((size_t)2 * D_MODEL * 4 * D_MODEL * 2); // 16MB ([Wk^T; Wv^T], 2048x4096)
  bf16* WoT   = (bf16*)alloc((size_t)D_MODEL * D_MODEL * 2);         // 2MB
  float* bkv  = (float*)alloc((size_t)2048 * 4);                     // 8KB
  bf16* q     = (bf16*)alloc((size_t)NTOK * D_MODEL * 2);            // 32MB (reused as attn-out)
  bf16* kv    = (bf16*)alloc((size_t)MTOK * 2048 * 2);               // 16MB (K | V fused, ldc=2048)
  bf16* vT    = (bf16*)alloc((size_t)MTOK * D_MODEL * 2);            // 8MB
  float* sc   = (float*)alloc((size_t)NTOK * 1024 * 4);              // 64MB
  bf16* attn  = (bf16*)alloc((size_t)NTOK * 1024 * 2);               // 32MB
  bf16* aout  = q;  // q dead after scores GEMM

  // 1) LayerNorm -> bf16
  ln_kernel<<<NTOK, 256, 0, stream>>>(x, ln_g, ln_b, xn);

  // 2) weight convert+transpose to (N,K) bf16 ; pack [bk;bv]
  transpose_to_bf16<float><<<dim3(32, 32, 1), dim3(32, 8), 0, stream>>>(Wq, WqT, 1024, 1024, 0, 0);
  transpose_to_bf16<float><<<dim3(32, 128, 1), dim3(32, 8), 0, stream>>>(Wk, WkvT, 1024, 4096, 0, 0);
  transpose_to_bf16<float><<<dim3(32, 128, 1), dim3(32, 8), 0, stream>>>(
      Wv, WkvT + (size_t)1024 * 4096, 1024, 4096, 0, 0);
  transpose_to_bf16<float><<<dim3(32, 32, 1), dim3(32, 8), 0, stream>>>(Wo, WoT, 1024, 1024, 0, 0);
  pack2<<<8, 256, 0, stream>>>(bk, bv, bkv);

  // 3) Q = xn @ Wq + bq    (16384,1024) K=1024
  gemm8p<bf16, true><<<dim3(4, 64, 1), 512, 0, stream>>>(
      xn, WqT, q, bq, 1.f, 1024, 1024, 1024, 1024, 0, 0, 0);

  // 4) [K|V] = xr @ [Wk|Wv] + [bk|bv]   (4096,2048) K=4096
  gemm8p<bf16, true><<<dim3(8, 16, 1), 512, 0, stream>>>(
      xn, WkvT, kv, bkv, 1.f, 4096, 4096, 4096, 2048, 0, 0, 0);

  // 5) vT per batch: (1024 tokens x 1024 dims)@2048 -> (1024 dims x 1024 tokens)
  transpose_to_bf16<bf16><<<dim3(32, 32, BATCH), dim3(32, 8), 0, stream>>>(
      kv + 1024, vT, 2048, 1024, (size_t)1024 * 2048, (size_t)1024 * 1024);

  // 6) scores = (q @ k^T)/32   batched fp32
  gemm8p<float, false><<<dim3(4, 16, 4), 512, 0, stream>>>(
      q, kv, sc, nullptr, 0.03125f, 1024, 1024, 2048, 1024,
      (size_t)4096 * 1024, (size_t)1024 * 2048, (size_t)4096 * 1024);

  // 7) softmax -> bf16
  softmax_kernel<<<NTOK, 256, 0, stream>>>(sc, attn);

  // 8) attn @ v   batched bf16 (into q's buffer)
  gemm8p<bf16, false><<<dim3(4, 16, 4), 512, 0, stream>>>(
      attn, vT, aout, nullptr, 1.f, 1024, 1024, 1024, 1024,
      (size_t)4096 * 1024, (size_t)1024 * 1024, (size_t)4096 * 1024);

  // 9) out = aout @ Wo + bo   fp32
  gemm8p<float, true><<<dim3(4, 64, 1), 512, 0, stream>>>(
      aout, WoT, out, bo, 1.f, 1024, 1024, 1024, 1024, 0, 0, 0);
}

// Round 4
// 418.192 us; speedup vs baseline: 1.3883x; 1.1328x over previous
//
#include <hip/hip_runtime.h>
#include <hip/hip_bf16.h>
#include <stdint.h>

typedef __bf16 bf16x8 __attribute__((ext_vector_type(8)));
typedef float f32x4 __attribute__((ext_vector_type(4)));
typedef __hip_bfloat16 bf16;

#define D_MODEL 1024
#define BATCH 4
#define NSEQ 4096
#define NTOK (BATCH * NSEQ)            // 16384
#define MTOK (BATCH * (NSEQ / 4))      // 4096

// ---------------- async global->LDS (16B per lane) ----------------
__device__ __forceinline__ void async_copy16(const void* g, void* l) {
  __builtin_amdgcn_global_load_lds(
      (const __attribute__((address_space(1))) void*)g,
      (__attribute__((address_space(3))) void*)l, 16, 0, 0);
}

__device__ __forceinline__ float to_f32(float v) { return v; }
__device__ __forceinline__ float to_f32(bf16 v) { return __bfloat162float(v); }

// ---------------- LayerNorm: fp32 in -> bf16 out ----------------
__global__ __launch_bounds__(256) void ln_kernel(
    const float* __restrict__ x, const float* __restrict__ g,
    const float* __restrict__ b, bf16* __restrict__ xn) {
  const size_t row = blockIdx.x;
  const float4* xr = (const float4*)(x + row * D_MODEL);
  const int tid = threadIdx.x;
  float4 v = xr[tid];
  float s = v.x + v.y + v.z + v.w;
  float sq = v.x * v.x + v.y * v.y + v.z * v.z + v.w * v.w;
#pragma unroll
  for (int o = 1; o < 64; o <<= 1) {
    s += __shfl_xor(s, o);
    sq += __shfl_xor(sq, o);
  }
  __shared__ float rs[4], rq[4];
  if ((tid & 63) == 0) { rs[tid >> 6] = s; rq[tid >> 6] = sq; }
  __syncthreads();
  s = rs[0] + rs[1] + rs[2] + rs[3];
  sq = rq[0] + rq[1] + rq[2] + rq[3];
  const float mu = s * (1.f / D_MODEL);
  const float var = sq * (1.f / D_MODEL) - mu * mu;
  const float rstd = rsqrtf(var + 1e-5f);
  float4 gv = ((const float4*)g)[tid];
  float4 bv = ((const float4*)b)[tid];
  union { ushort4 u; bf16 h[4]; } pk;
  pk.h[0] = __float2bfloat16((v.x - mu) * rstd * gv.x + bv.x);
  pk.h[1] = __float2bfloat16((v.y - mu) * rstd * gv.y + bv.y);
  pk.h[2] = __float2bfloat16((v.z - mu) * rstd * gv.z + bv.z);
  pk.h[3] = __float2bfloat16((v.w - mu) * rstd * gv.w + bv.w);
  ((ushort4*)(xn + row * D_MODEL))[tid] = pk.u;
}

// ---------------- transpose (R,C)@ldin -> (C,R)@ldout, bf16 out ----------------
template <typename T>
__global__ __launch_bounds__(256) void transpose_to_bf16(
    const T* __restrict__ in, bf16* __restrict__ out, int ldin, int ldout,
    size_t inStride, size_t outStride) {
  __shared__ bf16 tile[32][33];
  const int tx = threadIdx.x;  // 0..31
  const int ty = threadIdx.y;  // 0..7
  const int c0 = blockIdx.x * 32;
  const int r0 = blockIdx.y * 32;
  const T* ip = in + (size_t)blockIdx.z * inStride;
  bf16* op = out + (size_t)blockIdx.z * outStride;
#pragma unroll
  for (int i = 0; i < 4; i++) {
    const int r = r0 + ty + i * 8;
    tile[ty + i * 8][tx] = __float2bfloat16(to_f32(ip[(size_t)r * ldin + c0 + tx]));
  }
  __syncthreads();
#pragma unroll
  for (int i = 0; i < 4; i++) {
    const int oc = c0 + ty + i * 8;
    op[(size_t)oc * ldout + r0 + tx] = tile[tx][ty + i * 8];
  }
}

// ---------------- bias concat [a;b] (1024 each) ----------------
__global__ __launch_bounds__(256) void pack2(const float* __restrict__ a,
                                             const float* __restrict__ b,
                                             float* __restrict__ o) {
  const int i = blockIdx.x * 256 + threadIdx.x;
  o[i] = (i < 1024) ? a[i] : b[i - 1024];
}

// ---------------- row softmax: fp32 scores -> bf16 probs ----------------
__global__ __launch_bounds__(256) void softmax_kernel(
    const float* __restrict__ S, bf16* __restrict__ P) {
  const size_t row = blockIdx.x;
  const float4* sp = (const float4*)(S + row * 1024);
  const int tid = threadIdx.x;
  float4 v = sp[tid];
  float mx = fmaxf(fmaxf(v.x, v.y), fmaxf(v.z, v.w));
#pragma unroll
  for (int o = 1; o < 64; o <<= 1) mx = fmaxf(mx, __shfl_xor(mx, o));
  __shared__ float red[4];
  __shared__ float red2[4];
  if ((tid & 63) == 0) red[tid >> 6] = mx;
  __syncthreads();
  mx = fmaxf(fmaxf(red[0], red[1]), fmaxf(red[2], red[3]));
  const float e0 = __expf(v.x - mx), e1 = __expf(v.y - mx);
  const float e2 = __expf(v.z - mx), e3 = __expf(v.w - mx);
  float s = e0 + e1 + e2 + e3;
#pragma unroll
  for (int o = 1; o < 64; o <<= 1) s += __shfl_xor(s, o);
  if ((tid & 63) == 0) red2[tid >> 6] = s;
  __syncthreads();
  s = red2[0] + red2[1] + red2[2] + red2[3];
  const float inv = 1.f / s;
  union { ushort4 u; bf16 h[4]; } pk;
  pk.h[0] = __float2bfloat16(e0 * inv);
  pk.h[1] = __float2bfloat16(e1 * inv);
  pk.h[2] = __float2bfloat16(e2 * inv);
  pk.h[3] = __float2bfloat16(e3 * inv);
  ((ushort4*)(P + row * 1024))[tid] = pk.u;
}

// ---------------- 8-phase GEMM: C = scale*(A @ Bt^T) + bias ----------
// MFR = m-fragments per wave: 8 -> BM=256, 4 -> BM=128. BN=256, BK=64.
// 8 waves (2M x 4N). st_16x32 LDS swizzle (linear dest + inverse-swizzled
// global source + swizzled ds_read). Quadrant order (0,0),(0,1),(1,0),(1,1).
//
// CORRECTED read map (round-3 post-mortem): staged halves are ROW BLOCKS,
// per-wave fragment reads land in the staged half owned by the wave's wr/wc.
// So EVERY staged A half is read in P1 AND P3; every staged B half in P1
// AND P2.  =>  A-stages of a buffer legal only >= P4; B-stages >= P3.
// Stage placement (target : legal-from : placed):
//   buf1.B1(kt+1) : prev-P7 : P1   | buf0.B0(kt+2) : P3 : P3
//   buf0.B1(kt+2) : P3 : P4        | buf0.A0(kt+2) : P4 : P5
//   buf0.A1(kt+2) : P4 : P6        | buf1.B0(kt+3) : P7 : P7
//   buf1.A0+A1(kt+3) : P8 : P8
// vmcnt ledger (issue order per thread = macro order):
//   P4: newer-than-tile(kt+1) = P3.B0(2)+P4.B1(2) = 4        -> vmcnt(4)
//   P8: newer-than-tile(kt+2) = P7.B0(2)+P8.A0A1(2AL) = 2+2AL -> vmcnt(6|4)
// Both drains land exactly one full tile before its first read.
template <typename CT, bool HAS_BIAS, int MFR>
__global__ __launch_bounds__(512, 1) void gemm8p(
    const bf16* __restrict__ A, const bf16* __restrict__ Bt,
    CT* __restrict__ C, const float* __restrict__ bias, float scale,
    int K, int lda, int ldb, int ldc,
    size_t aStride, size_t bStride, size_t cStride) {
  constexpr int BM = MFR * 32;
  constexpr int AHALF = MFR * 2048;   // bytes per A half-tile (BM/2 rows x 128B)
  constexpr int ABUF = MFR * 4096;    // A bytes per buffer
  constexpr int BUFS = ABUF + 32768;  // bytes per buffer (A + B)
  constexpr int AL = MFR / 4;         // global_load_lds insts/thread per A-half
  __shared__ __align__(128) char lds[2 * BUFS];

  const int tid = threadIdx.x;
  const int lane = tid & 63;
  const int wid = tid >> 6;   // 0..7
  const int wr = wid >> 2;    // 0..1  (M half)
  const int wc = wid & 3;     // 0..3  (N quarter)

  // XCD-chunked bijective block swizzle (all grids here are pow2, nwg%8==0)
  const int nx = gridDim.x, ny = gridDim.y;
  const int shx = __popc(nx - 1), shy = __popc(ny - 1);
  const int lxy = nx * ny;
  int lin = blockIdx.x + nx * blockIdx.y + lxy * blockIdx.z;
  const int nwg = lxy * gridDim.z;
  lin = (lin & 7) * (nwg >> 3) + (lin >> 3);
  const int bx = lin & (nx - 1);
  const int by = (lin >> shx) & (ny - 1);
  const int bz = lin >> (shx + shy);

  const int bn0 = bx * 256;
  const int bm0 = by * BM;
  A += (size_t)bz * aStride;
  Bt += (size_t)bz * bStride;
  C += (size_t)bz * cStride;

  // staging: physical slot o (linear, global_load_lds dest); logical (r,c)
  // via the st_16x32 involution L = o ^ (((o>>9)&1)<<5).
  const bf16* pa[AL];
  int loA[AL];
  const bf16* pb[2];
  int loB[2];
#pragma unroll
  for (int j = 0; j < AL; j++) {
    const int o = tid * 16 + j * 8192;
    const int L = o ^ (((o >> 9) & 1) << 5);
    pa[j] = A + (size_t)(bm0 + (L >> 7)) * lda + ((L & 127) >> 1);
    loA[j] = o;
  }
#pragma unroll
  for (int j = 0; j < 2; j++) {
    const int o = tid * 16 + j * 8192;
    const int L = o ^ (((o >> 9) & 1) << 5);
    pb[j] = Bt + (size_t)(bn0 + (L >> 7)) * ldb + ((L & 127) >> 1);
    loB[j] = o;
  }

  // swizzled ds_read bases (swizzle bit = row bit 2; all added offsets are
  // multiples of 16 rows or <128B within-row, so the bit is base-computable)
  const int arow = wr * (MFR * 16) + (lane & 15);
  const int brow = wc * 64 + (lane & 15);
  const int aRd = (arow * 128 + (lane >> 4) * 16) ^ (((arow >> 2) & 1) << 5);
  const int bRd = (brow * 128 + (lane >> 4) * 16) ^ (((brow >> 2) & 1) << 5);

  bf16x8 Ah[MFR / 2][2];       // one A fragment-half
  bf16x8 B0f[2][2], B1f[2][2]; // B n-frags 0,1 and 2,3
  f32x4 acc[MFR][4];
#pragma unroll
  for (int m = 0; m < MFR; m++)
#pragma unroll
    for (int n = 0; n < 4; n++) acc[m][n] = (f32x4){0.f, 0.f, 0.f, 0.f};

#define STAGE_A(b, h, kt) { const size_t go = (size_t)((h) * (BM / 2)) * lda + (size_t)(kt) * 64; \
  _Pragma("unroll") for (int j = 0; j < AL; j++) \
    async_copy16(pa[j] + go, lds + (b) * BUFS + (h) * AHALF + loA[j]); }
#define STAGE_B(b, h, kt) { const size_t go = (size_t)((h) * 128) * ldb + (size_t)(kt) * 64; \
  _Pragma("unroll") for (int j = 0; j < 2; j++) \
    async_copy16(pb[j] + go, lds + (b) * BUFS + ABUF + (h) * 16384 + loB[j]); }
#define READ_A(b, h) _Pragma("unroll") for (int m2 = 0; m2 < MFR / 2; m2++) \
  _Pragma("unroll") for (int kk = 0; kk < 2; kk++) \
    Ah[m2][kk] = *(const bf16x8*)(lds + (b) * BUFS + (aRd + ((h) * (MFR / 2) + m2) * 2048 + kk * 64));
#define READ_B0(b) _Pragma("unroll") for (int n2 = 0; n2 < 2; n2++) \
  _Pragma("unroll") for (int kk = 0; kk < 2; kk++) \
    B0f[n2][kk] = *(const bf16x8*)(lds + (b) * BUFS + ABUF + (bRd + n2 * 2048 + kk * 64));
#define READ_B1(b) _Pragma("unroll") for (int n2 = 0; n2 < 2; n2++) \
  _Pragma("unroll") for (int kk = 0; kk < 2; kk++) \
    B1f[n2][kk] = *(const bf16x8*)(lds + (b) * BUFS + ABUF + (bRd + (2 + n2) * 2048 + kk * 64));
#define MFMA_Q(MH, NH, BF) { __builtin_amdgcn_s_setprio(1); \
  _Pragma("unroll") for (int m2 = 0; m2 < MFR / 2; m2++) \
  _Pragma("unroll") for (int n2 = 0; n2 < 2; n2++) \
  _Pragma("unroll") for (int kk = 0; kk < 2; kk++) \
    acc[(MH) * (MFR / 2) + m2][(NH) * 2 + n2] = __builtin_amdgcn_mfma_f32_16x16x32_bf16( \
        Ah[m2][kk], BF[n2][kk], acc[(MH) * (MFR / 2) + m2][(NH) * 2 + n2], 0, 0, 0); \
  __builtin_amdgcn_s_setprio(0); }
#define BARR() { __builtin_amdgcn_sched_barrier(0); __builtin_amdgcn_s_barrier(); __builtin_amdgcn_sched_barrier(0); }
#define VMC4() { asm volatile("s_waitcnt vmcnt(4)" ::: "memory"); __builtin_amdgcn_sched_barrier(0); }
#define VMCN() { if constexpr (AL == 2) { asm volatile("s_waitcnt vmcnt(6)" ::: "memory"); } \
                 else { asm volatile("s_waitcnt vmcnt(4)" ::: "memory"); } \
                 __builtin_amdgcn_sched_barrier(0); }
#define VMC0() { asm volatile("s_waitcnt vmcnt(0)" ::: "memory"); __builtin_amdgcn_sched_barrier(0); }

  // prologue: tile0 -> buf0 (4 halves), tile1 -> buf1 (A0,A1,B0)
  STAGE_A(0, 0, 0) STAGE_A(0, 1, 0) STAGE_B(0, 0, 0) STAGE_B(0, 1, 0)
  STAGE_A(1, 0, 1) STAGE_A(1, 1, 1) STAGE_B(1, 0, 1)
  VMCN()   // leaves tile1's 2AL+2 in flight; tile0 fully landed
  BARR()

  const int NIT = K >> 7;  // iterations of 2 K-tiles (BK=64 each)
  for (int it = 0; it < NIT - 1; ++it) {
    const int kt = it * 2;
    // P1 (t0 q00)
    READ_A(0, 0) READ_B0(0)
    STAGE_B(1, 1, kt + 1)
    BARR()
    MFMA_Q(0, 0, B0f)
    BARR()
    // P2 (t0 q01)
    READ_B1(0)
    BARR()
    MFMA_Q(0, 1, B1f)
    BARR()
    // P3 (t0 q10)
    READ_A(0, 1)
    STAGE_B(0, 0, kt + 2)
    BARR()
    MFMA_Q(1, 0, B0f)
    BARR()
    // P4 (t0 q11)
    STAGE_B(0, 1, kt + 2)
    VMC4()   // tile kt+1 (buf1) fully landed before P5 reads it
    BARR()
    MFMA_Q(1, 1, B1f)
    BARR()
    // P5 (t1 q00)
    READ_A(1, 0) READ_B0(1)
    STAGE_A(0, 0, kt + 2)
    BARR()
    MFMA_Q(0, 0, B0f)
    BARR()
    // P6 (t1 q01)
    READ_B1(1)
    STAGE_A(0, 1, kt + 2)
    BARR()
    MFMA_Q(0, 1, B1f)
    BARR()
    // P7 (t1 q10)
    READ_A(1, 1)
    STAGE_B(1, 0, kt + 3)
    BARR()
    MFMA_Q(1, 0, B0f)
    BARR()
    // P8 (t1 q11)
    STAGE_A(1, 0, kt + 3) STAGE_A(1, 1, kt + 3)
    VMCN()   // tile kt+2 (buf0) fully landed before next-P1 reads it
    BARR()
    MFMA_Q(1, 1, B1f)
    BARR()
  }
  // final iteration: tiles 2*NIT-2 (buf0), 2*NIT-1 (buf1; B1 staged here)
  {
    READ_A(0, 0) READ_B0(0)
    STAGE_B(1, 1, 2 * NIT - 1)
    BARR()
    MFMA_Q(0, 0, B0f)
    BARR()
    READ_B1(0)
    BARR()
    MFMA_Q(0, 1, B1f)
    BARR()
    READ_A(0, 1)
    BARR()
    MFMA_Q(1, 0, B0f)
    BARR()
    VMC0()   // buf1 (B0,A0,A1 from prev iter + B1 above) fully landed
    BARR()
    MFMA_Q(1, 1, B1f)
    BARR()
    READ_A(1, 0) READ_B0(1)
    MFMA_Q(0, 0, B0f)
    READ_B1(1)
    MFMA_Q(0, 1, B1f)
    READ_A(1, 1)
    MFMA_Q(1, 0, B0f)
    MFMA_Q(1, 1, B1f)
  }
#undef STAGE_A
#undef STAGE_B
#undef READ_A
#undef READ_B0
#undef READ_B1
#undef MFMA_Q
#undef BARR
#undef VMC4
#undef VMCN
#undef VMC0

  // epilogue: C/D layout col=lane&15, row=(lane>>4)*4+j
  const int cl = lane & 15;
  const int rg = lane >> 4;
#pragma unroll
  for (int m = 0; m < MFR; m++) {
#pragma unroll
    for (int n = 0; n < 4; n++) {
      const int col = bn0 + wc * 64 + n * 16 + cl;
      const float bv = HAS_BIAS ? bias[col] : 0.f;
#pragma unroll
      for (int j = 0; j < 4; j++) {
        const int row = bm0 + wr * (MFR * 16) + m * 16 + rg * 4 + j;
        const float v = acc[m][n][j] * scale + bv;
        if constexpr (sizeof(CT) == 2)
          C[(size_t)row * ldc + col] = __float2bfloat16(v);
        else
          C[(size_t)row * ldc + col] = v;
      }
    }
  }
}

extern "C" void kernel_launch(void* const* d_in, const int* in_sizes, int n_in,
                              void* d_out, int out_size, void* d_ws, size_t ws_size,
                              hipStream_t stream) {
  const float* x = (const float*)d_in[0];
  const float* ln_g = (const float*)d_in[1];
  const float* ln_b = (const float*)d_in[2];
  const float* Wq = (const float*)d_in[3];
  const float* bq = (const float*)d_in[4];
  const float* Wk = (const float*)d_in[5];
  const float* bk = (const float*)d_in[6];
  const float* Wv = (const float*)d_in[7];
  const float* bv = (const float*)d_in[8];
  const float* Wo = (const float*)d_in[9];
  const float* bo = (const float*)d_in[10];
  float* out = (float*)d_out;

  char* w = (char*)d_ws;
  auto alloc = [&](size_t bytes) {
    char* p = w;
    w += (bytes + 255) & ~(size_t)255;
    return p;
  };
  bf16* xn    = (bf16*)alloc((size_t)NTOK * D_MODEL * 2);            // 32MB
  bf16* WqT   = (bf16*)alloc((size_t)D_MODEL * D_MODEL * 2);         // 2MB
  bf16* WkvT  = (bf16*)alloc((size_t)2 * D_MODEL * 4 * D_MODEL * 2); // 16MB
  bf16* WoT   = (bf16*)alloc((size_t)D_MODEL * D_MODEL * 2);         // 2MB
  float* bkv  = (float*)alloc((size_t)2048 * 4);                     // 8KB
  bf16* q     = (bf16*)alloc((size_t)NTOK * D_MODEL * 2);            // 32MB (reused as attn-out)
  bf16* kv    = (bf16*)alloc((size_t)MTOK * 2048 * 2);               // 16MB (K | V, ldc=2048)
  bf16* vT    = (bf16*)alloc((size_t)MTOK * D_MODEL * 2);            // 8MB
  float* sc   = (float*)alloc((size_t)NTOK * 1024 * 4);              // 64MB
  bf16* attn  = (bf16*)alloc((size_t)NTOK * 1024 * 2);               // 32MB
  bf16* aout  = q;  // q dead after scores GEMM

  // 1) LayerNorm -> bf16
  ln_kernel<<<NTOK, 256, 0, stream>>>(x, ln_g, ln_b, xn);

  // 2) weight convert+transpose to (N,K) bf16 ; pack [bk;bv]
  transpose_to_bf16<float><<<dim3(32, 32, 1), dim3(32, 8), 0, stream>>>(Wq, WqT, 1024, 1024, 0, 0);
  transpose_to_bf16<float><<<dim3(32, 128, 1), dim3(32, 8), 0, stream>>>(Wk, WkvT, 1024, 4096, 0, 0);
  transpose_to_bf16<float><<<dim3(32, 128, 1), dim3(32, 8), 0, stream>>>(
      Wv, WkvT + (size_t)1024 * 4096, 1024, 4096, 0, 0);
  transpose_to_bf16<float><<<dim3(32, 32, 1), dim3(32, 8), 0, stream>>>(Wo, WoT, 1024, 1024, 0, 0);
  pack2<<<8, 256, 0, stream>>>(bk, bv, bkv);

  // 3) Q = xn @ Wq + bq    (16384,1024) K=1024, grid 256
  gemm8p<bf16, true, 8><<<dim3(4, 64, 1), 512, 0, stream>>>(
      xn, WqT, q, bq, 1.f, 1024, 1024, 1024, 1024, 0, 0, 0);

  // 4) [K|V] = xr @ [Wk|Wv] + [bk|bv]   (4096,2048) K=4096, BM=128 -> grid 256
  gemm8p<bf16, true, 4><<<dim3(8, 32, 1), 512, 0, stream>>>(
      xn, WkvT, kv, bkv, 1.f, 4096, 4096, 4096, 2048, 0, 0, 0);

  // 5) vT per batch: (1024 x 1024)@2048 -> transposed @1024
  transpose_to_bf16<bf16><<<dim3(32, 32, BATCH), dim3(32, 8), 0, stream>>>(
      kv + 1024, vT, 2048, 1024, (size_t)1024 * 2048, (size_t)1024 * 1024);

  // 6) scores = (q @ k^T)/32   batched fp32, grid 256
  gemm8p<float, false, 8><<<dim3(4, 16, 4), 512, 0, stream>>>(
      q, kv, sc, nullptr, 0.03125f, 1024, 1024, 2048, 1024,
      (size_t)4096 * 1024, (size_t)1024 * 2048, (size_t)4096 * 1024);

  // 7) softmax -> bf16
  softmax_kernel<<<NTOK, 256, 0, stream>>>(sc, attn);

  // 8) attn @ v   batched bf16 (into q's buffer), grid 256
  gemm8p<bf16, false, 8><<<dim3(4, 16, 4), 512, 0, stream>>>(
      attn, vT, aout, nullptr, 1.f, 1024, 1024, 1024, 1024,
      (size_t)4096 * 1024, (size_t)1024 * 1024, (size_t)4096 * 1024);

  // 9) out = aout @ Wo + bo   fp32, grid 256
  gemm8p<float, true, 8><<<dim3(4, 64, 1), 512, 0, stream>>>(
      aout, WoT, out, bo, 1.f, 1024, 1024, 1024, 1024, 0, 0, 0);
}

// Round 6
// 401.817 us; speedup vs baseline: 1.4449x; 1.0408x over previous
//
#include <hip/hip_runtime.h>
#include <hip/hip_bf16.h>
#include <stdint.h>

typedef __bf16 bf16x8 __attribute__((ext_vector_type(8)));
typedef float f32x4 __attribute__((ext_vector_type(4)));
typedef __hip_bfloat16 bf16;

#define D_MODEL 1024
#define BATCH 4
#define NSEQ 4096
#define NTOK (BATCH * NSEQ)            // 16384
#define MTOK (BATCH * (NSEQ / 4))      // 4096

// ---------------- async global->LDS (16B per lane) ----------------
__device__ __forceinline__ void async_copy16(const void* g, void* l) {
  __builtin_amdgcn_global_load_lds(
      (const __attribute__((address_space(1))) void*)g,
      (__attribute__((address_space(3))) void*)l, 16, 0, 0);
}

__device__ __forceinline__ float to_f32(float v) { return v; }
__device__ __forceinline__ float to_f32(bf16 v) { return __bfloat162float(v); }

// ---------------- LayerNorm: fp32 in -> bf16 out ----------------
__global__ __launch_bounds__(256) void ln_kernel(
    const float* __restrict__ x, const float* __restrict__ g,
    const float* __restrict__ b, bf16* __restrict__ xn) {
  const size_t row = blockIdx.x;
  const float4* xr = (const float4*)(x + row * D_MODEL);
  const int tid = threadIdx.x;
  float4 v = xr[tid];
  float s = v.x + v.y + v.z + v.w;
  float sq = v.x * v.x + v.y * v.y + v.z * v.z + v.w * v.w;
#pragma unroll
  for (int o = 1; o < 64; o <<= 1) {
    s += __shfl_xor(s, o);
    sq += __shfl_xor(sq, o);
  }
  __shared__ float rs[4], rq[4];
  if ((tid & 63) == 0) { rs[tid >> 6] = s; rq[tid >> 6] = sq; }
  __syncthreads();
  s = rs[0] + rs[1] + rs[2] + rs[3];
  sq = rq[0] + rq[1] + rq[2] + rq[3];
  const float mu = s * (1.f / D_MODEL);
  const float var = sq * (1.f / D_MODEL) - mu * mu;
  const float rstd = rsqrtf(var + 1e-5f);
  float4 gv = ((const float4*)g)[tid];
  float4 bv = ((const float4*)b)[tid];
  union { ushort4 u; bf16 h[4]; } pk;
  pk.h[0] = __float2bfloat16((v.x - mu) * rstd * gv.x + bv.x);
  pk.h[1] = __float2bfloat16((v.y - mu) * rstd * gv.y + bv.y);
  pk.h[2] = __float2bfloat16((v.z - mu) * rstd * gv.z + bv.z);
  pk.h[3] = __float2bfloat16((v.w - mu) * rstd * gv.w + bv.w);
  ((ushort4*)(xn + row * D_MODEL))[tid] = pk.u;
}

// ---------------- transpose (R,C)@ldin -> (C,R)@ldout, bf16 out ----------------
template <typename T>
__global__ __launch_bounds__(256) void transpose_to_bf16(
    const T* __restrict__ in, bf16* __restrict__ out, int ldin, int ldout,
    size_t inStride, size_t outStride) {
  __shared__ bf16 tile[32][33];
  const int tx = threadIdx.x;  // 0..31
  const int ty = threadIdx.y;  // 0..7
  const int c0 = blockIdx.x * 32;
  const int r0 = blockIdx.y * 32;
  const T* ip = in + (size_t)blockIdx.z * inStride;
  bf16* op = out + (size_t)blockIdx.z * outStride;
#pragma unroll
  for (int i = 0; i < 4; i++) {
    const int r = r0 + ty + i * 8;
    tile[ty + i * 8][tx] = __float2bfloat16(to_f32(ip[(size_t)r * ldin + c0 + tx]));
  }
  __syncthreads();
#pragma unroll
  for (int i = 0; i < 4; i++) {
    const int oc = c0 + ty + i * 8;
    op[(size_t)oc * ldout + r0 + tx] = tile[tx][ty + i * 8];
  }
}

// ---------------- bias concat [a;b] (1024 each) ----------------
__global__ __launch_bounds__(256) void pack2(const float* __restrict__ a,
                                             const float* __restrict__ b,
                                             float* __restrict__ o) {
  const int i = blockIdx.x * 256 + threadIdx.x;
  o[i] = (i < 1024) ? a[i] : b[i - 1024];
}

// ---------------- row softmax: fp32 scores -> bf16 probs ----------------
__global__ __launch_bounds__(256) void softmax_kernel(
    const float* __restrict__ S, bf16* __restrict__ P) {
  const size_t row = blockIdx.x;
  const float4* sp = (const float4*)(S + row * 1024);
  const int tid = threadIdx.x;
  float4 v = sp[tid];
  float mx = fmaxf(fmaxf(v.x, v.y), fmaxf(v.z, v.w));
#pragma unroll
  for (int o = 1; o < 64; o <<= 1) mx = fmaxf(mx, __shfl_xor(mx, o));
  __shared__ float red[4];
  __shared__ float red2[4];
  if ((tid & 63) == 0) red[tid >> 6] = mx;
  __syncthreads();
  mx = fmaxf(fmaxf(red[0], red[1]), fmaxf(red[2], red[3]));
  const float e0 = __expf(v.x - mx), e1 = __expf(v.y - mx);
  const float e2 = __expf(v.z - mx), e3 = __expf(v.w - mx);
  float s = e0 + e1 + e2 + e3;
#pragma unroll
  for (int o = 1; o < 64; o <<= 1) s += __shfl_xor(s, o);
  if ((tid & 63) == 0) red2[tid >> 6] = s;
  __syncthreads();
  s = red2[0] + red2[1] + red2[2] + red2[3];
  const float inv = 1.f / s;
  union { ushort4 u; bf16 h[4]; } pk;
  pk.h[0] = __float2bfloat16(e0 * inv);
  pk.h[1] = __float2bfloat16(e1 * inv);
  pk.h[2] = __float2bfloat16(e2 * inv);
  pk.h[3] = __float2bfloat16(e3 * inv);
  ((ushort4*)(P + row * 1024))[tid] = pk.u;
}

// ---------------- 8-phase GEMM: C = scale*(A @ Bt^T) + bias ----------
// MFR = m-fragments per wave: 8 -> BM=256, 4 -> BM=128. BN=256, BK=64.
// 8 waves (2M x 4N). 3-BIT LDS swizzle (T2 recipe): logical byte
// (row*128 + col) stored at physical (row*128 + col) ^ ((row&7)<<4).
// 16 rows read at one col-slot by a 16-lane group -> 8 distinct 16B slots
// -> 2 lanes/bank (free). Applied as: linear global_load_lds dest +
// inverse-swizzled global source + swizzled ds_read (both sides, rule 21).
// ds_read bases precomputed per-kk because the mask (bits 4-6) overlaps
// kk*64; row-block offsets (multiples of 2048B = 16 rows) are carry-free
// past the mask and keep row&7 invariant.
//
// Stage/read hazard ledger (staged halves are ROW blocks; every A half is
// read in P1 AND P3, every B half in P1 AND P2 => A-stages >= P4 legal,
// B-stages >= P3):
//   buf1.B1(kt+1) : P1   | buf0.B0(kt+2) : P3 | buf0.B1(kt+2) : P4
//   buf0.A0(kt+2) : P5   | buf0.A1(kt+2) : P6 | buf1.B0(kt+3) : P7
//   buf1.A0+A1(kt+3) : P8
// vmcnt: P4 -> 4 (tile kt+1 landed), P8 -> 2+2*AL (tile kt+2 landed).
template <typename CT, bool HAS_BIAS, int MFR>
__global__ __launch_bounds__(512, 1) void gemm8p(
    const bf16* __restrict__ A, const bf16* __restrict__ Bt,
    CT* __restrict__ C, const float* __restrict__ bias, float scale,
    int K, int lda, int ldb, int ldc,
    size_t aStride, size_t bStride, size_t cStride) {
  constexpr int BM = MFR * 32;
  constexpr int AHALF = MFR * 2048;   // bytes per A half-tile (BM/2 rows x 128B)
  constexpr int ABUF = MFR * 4096;    // A bytes per buffer
  constexpr int BUFS = ABUF + 32768;  // bytes per buffer (A + B)
  constexpr int AL = MFR / 4;         // global_load_lds insts/thread per A-half
  __shared__ __align__(128) char lds[2 * BUFS];

  const int tid = threadIdx.x;
  const int lane = tid & 63;
  const int wid = tid >> 6;   // 0..7
  const int wr = wid >> 2;    // 0..1  (M half)
  const int wc = wid & 3;     // 0..3  (N quarter)

  // XCD-chunked bijective block swizzle (all grids here are pow2, nwg%8==0)
  const int nx = gridDim.x, ny = gridDim.y;
  const int shx = __popc(nx - 1), shy = __popc(ny - 1);
  const int lxy = nx * ny;
  int lin = blockIdx.x + nx * blockIdx.y + lxy * blockIdx.z;
  const int nwg = lxy * gridDim.z;
  lin = (lin & 7) * (nwg >> 3) + (lin >> 3);
  const int bx = lin & (nx - 1);
  const int by = (lin >> shx) & (ny - 1);
  const int bz = lin >> (shx + shy);

  const int bn0 = bx * 256;
  const int bm0 = by * BM;
  A += (size_t)bz * aStride;
  Bt += (size_t)bz * bStride;
  C += (size_t)bz * cStride;

  // staging: physical slot o (linear, global_load_lds dest); logical byte L
  // via the 3-bit involution L = o ^ (((o>>7)&7)<<4)  (row bits untouched).
  const bf16* pa[AL];
  int loA[AL];
  const bf16* pb[2];
  int loB[2];
#pragma unroll
  for (int j = 0; j < AL; j++) {
    const int o = tid * 16 + j * 8192;
    const int L = o ^ (((o >> 7) & 7) << 4);
    pa[j] = A + (size_t)(bm0 + (L >> 7)) * lda + ((L & 127) >> 1);
    loA[j] = o;
  }
#pragma unroll
  for (int j = 0; j < 2; j++) {
    const int o = tid * 16 + j * 8192;
    const int L = o ^ (((o >> 7) & 7) << 4);
    pb[j] = Bt + (size_t)(bn0 + (L >> 7)) * ldb + ((L & 127) >> 1);
    loB[j] = o;
  }

  // swizzled ds_read bases, one per kk (mask bits 4-6 overlap kk*64, so the
  // XOR is applied after the full column offset; 2048B-multiple additions
  // later are carry-free past the mask and preserve row&7)
  const int arow = wr * (MFR * 16) + (lane & 15);
  const int brow = wc * 64 + (lane & 15);
  const int aLin = arow * 128 + (lane >> 4) * 16;
  const int bLin = brow * 128 + (lane >> 4) * 16;
  const int aSw = (arow & 7) << 4;
  const int bSw = (brow & 7) << 4;
  const int aRd0 = aLin ^ aSw, aRd1 = (aLin + 64) ^ aSw;
  const int bRd0 = bLin ^ bSw, bRd1 = (bLin + 64) ^ bSw;

  bf16x8 Ah[MFR / 2][2];       // one A fragment-half
  bf16x8 B0f[2][2], B1f[2][2]; // B n-frags 0,1 and 2,3
  f32x4 acc[MFR][4];
#pragma unroll
  for (int m = 0; m < MFR; m++)
#pragma unroll
    for (int n = 0; n < 4; n++) acc[m][n] = (f32x4){0.f, 0.f, 0.f, 0.f};

#define STAGE_A(b, h, kt) { const size_t go = (size_t)((h) * (BM / 2)) * lda + (size_t)(kt) * 64; \
  _Pragma("unroll") for (int j = 0; j < AL; j++) \
    async_copy16(pa[j] + go, lds + (b) * BUFS + (h) * AHALF + loA[j]); }
#define STAGE_B(b, h, kt) { const size_t go = (size_t)((h) * 128) * ldb + (size_t)(kt) * 64; \
  _Pragma("unroll") for (int j = 0; j < 2; j++) \
    async_copy16(pb[j] + go, lds + (b) * BUFS + ABUF + (h) * 16384 + loB[j]); }
#define READ_A(b, h) _Pragma("unroll") for (int m2 = 0; m2 < MFR / 2; m2++) \
  _Pragma("unroll") for (int kk = 0; kk < 2; kk++) \
    Ah[m2][kk] = *(const bf16x8*)(lds + (b) * BUFS + ((kk ? aRd1 : aRd0) + ((h) * (MFR / 2) + m2) * 2048));
#define READ_B0(b) _Pragma("unroll") for (int n2 = 0; n2 < 2; n2++) \
  _Pragma("unroll") for (int kk = 0; kk < 2; kk++) \
    B0f[n2][kk] = *(const bf16x8*)(lds + (b) * BUFS + ABUF + ((kk ? bRd1 : bRd0) + n2 * 2048));
#define READ_B1(b) _Pragma("unroll") for (int n2 = 0; n2 < 2; n2++) \
  _Pragma("unroll") for (int kk = 0; kk < 2; kk++) \
    B1f[n2][kk] = *(const bf16x8*)(lds + (b) * BUFS + ABUF + ((kk ? bRd1 : bRd0) + (2 + n2) * 2048));
#define MFMA_Q(MH, NH, BF) { __builtin_amdgcn_s_setprio(1); \
  _Pragma("unroll") for (int m2 = 0; m2 < MFR / 2; m2++) \
  _Pragma("unroll") for (int n2 = 0; n2 < 2; n2++) \
  _Pragma("unroll") for (int kk = 0; kk < 2; kk++) \
    acc[(MH) * (MFR / 2) + m2][(NH) * 2 + n2] = __builtin_amdgcn_mfma_f32_16x16x32_bf16( \
        Ah[m2][kk], BF[n2][kk], acc[(MH) * (MFR / 2) + m2][(NH) * 2 + n2], 0, 0, 0); \
  __builtin_amdgcn_s_setprio(0); }
#define BARR() { __builtin_amdgcn_sched_barrier(0); __builtin_amdgcn_s_barrier(); __builtin_amdgcn_sched_barrier(0); }
#define VMC4() { asm volatile("s_waitcnt vmcnt(4)" ::: "memory"); __builtin_amdgcn_sched_barrier(0); }
#define VMCN() { if constexpr (AL == 2) { asm volatile("s_waitcnt vmcnt(6)" ::: "memory"); } \
                 else { asm volatile("s_waitcnt vmcnt(4)" ::: "memory"); } \
                 __builtin_amdgcn_sched_barrier(0); }
#define VMC0() { asm volatile("s_waitcnt vmcnt(0)" ::: "memory"); __builtin_amdgcn_sched_barrier(0); }

  // prologue: tile0 -> buf0 (4 halves), tile1 -> buf1 (A0,A1,B0)
  STAGE_A(0, 0, 0) STAGE_A(0, 1, 0) STAGE_B(0, 0, 0) STAGE_B(0, 1, 0)
  STAGE_A(1, 0, 1) STAGE_A(1, 1, 1) STAGE_B(1, 0, 1)
  VMCN()   // leaves tile1's 2AL+2 in flight; tile0 fully landed
  BARR()

  const int NIT = K >> 7;  // iterations of 2 K-tiles (BK=64 each)
  for (int it = 0; it < NIT - 1; ++it) {
    const int kt = it * 2;
    // P1 (t0 q00)
    READ_A(0, 0) READ_B0(0)
    STAGE_B(1, 1, kt + 1)
    BARR()
    MFMA_Q(0, 0, B0f)
    BARR()
    // P2 (t0 q01)
    READ_B1(0)
    BARR()
    MFMA_Q(0, 1, B1f)
    BARR()
    // P3 (t0 q10)
    READ_A(0, 1)
    STAGE_B(0, 0, kt + 2)
    BARR()
    MFMA_Q(1, 0, B0f)
    BARR()
    // P4 (t0 q11)
    STAGE_B(0, 1, kt + 2)
    VMC4()   // tile kt+1 (buf1) fully landed before P5 reads it
    BARR()
    MFMA_Q(1, 1, B1f)
    BARR()
    // P5 (t1 q00)
    READ_A(1, 0) READ_B0(1)
    STAGE_A(0, 0, kt + 2)
    BARR()
    MFMA_Q(0, 0, B0f)
    BARR()
    // P6 (t1 q01)
    READ_B1(1)
    STAGE_A(0, 1, kt + 2)
    BARR()
    MFMA_Q(0, 1, B1f)
    BARR()
    // P7 (t1 q10)
    READ_A(1, 1)
    STAGE_B(1, 0, kt + 3)
    BARR()
    MFMA_Q(1, 0, B0f)
    BARR()
    // P8 (t1 q11)
    STAGE_A(1, 0, kt + 3) STAGE_A(1, 1, kt + 3)
    VMCN()   // tile kt+2 (buf0) fully landed before next-P1 reads it
    BARR()
    MFMA_Q(1, 1, B1f)
    BARR()
  }
  // final iteration: tiles 2*NIT-2 (buf0), 2*NIT-1 (buf1; B1 staged here)
  {
    READ_A(0, 0) READ_B0(0)
    STAGE_B(1, 1, 2 * NIT - 1)
    BARR()
    MFMA_Q(0, 0, B0f)
    BARR()
    READ_B1(0)
    BARR()
    MFMA_Q(0, 1, B1f)
    BARR()
    READ_A(0, 1)
    BARR()
    MFMA_Q(1, 0, B0f)
    BARR()
    VMC0()   // buf1 (B0,A0,A1 from prev iter + B1 above) fully landed
    BARR()
    MFMA_Q(1, 1, B1f)
    BARR()
    READ_A(1, 0) READ_B0(1)
    MFMA_Q(0, 0, B0f)
    READ_B1(1)
    MFMA_Q(0, 1, B1f)
    READ_A(1, 1)
    MFMA_Q(1, 0, B0f)
    MFMA_Q(1, 1, B1f)
  }
#undef STAGE_A
#undef STAGE_B
#undef READ_A
#undef READ_B0
#undef READ_B1
#undef MFMA_Q
#undef BARR
#undef VMC4
#undef VMCN
#undef VMC0

  // epilogue: C/D layout col=lane&15, row=(lane>>4)*4+j
  const int cl = lane & 15;
  const int rg = lane >> 4;
#pragma unroll
  for (int m = 0; m < MFR; m++) {
#pragma unroll
    for (int n = 0; n < 4; n++) {
      const int col = bn0 + wc * 64 + n * 16 + cl;
      const float bv = HAS_BIAS ? bias[col] : 0.f;
#pragma unroll
      for (int j = 0; j < 4; j++) {
        const int row = bm0 + wr * (MFR * 16) + m * 16 + rg * 4 + j;
        const float v = acc[m][n][j] * scale + bv;
        if constexpr (sizeof(CT) == 2)
          C[(size_t)row * ldc + col] = __float2bfloat16(v);
        else
          C[(size_t)row * ldc + col] = v;
      }
    }
  }
}

extern "C" void kernel_launch(void* const* d_in, const int* in_sizes, int n_in,
                              void* d_out, int out_size, void* d_ws, size_t ws_size,
                              hipStream_t stream) {
  const float* x = (const float*)d_in[0];
  const float* ln_g = (const float*)d_in[1];
  const float* ln_b = (const float*)d_in[2];
  const float* Wq = (const float*)d_in[3];
  const float* bq = (const float*)d_in[4];
  const float* Wk = (const float*)d_in[5];
  const float* bk = (const float*)d_in[6];
  const float* Wv = (const float*)d_in[7];
  const float* bv = (const float*)d_in[8];
  const float* Wo = (const float*)d_in[9];
  const float* bo = (const float*)d_in[10];
  float* out = (float*)d_out;

  char* w = (char*)d_ws;
  auto alloc = [&](size_t bytes) {
    char* p = w;
    w += (bytes + 255) & ~(size_t)255;
    return p;
  };
  bf16* xn    = (bf16*)alloc((size_t)NTOK * D_MODEL * 2);            // 32MB
  bf16* WqT   = (bf16*)alloc((size_t)D_MODEL * D_MODEL * 2);         // 2MB
  bf16* WkvT  = (bf16*)alloc((size_t)2 * D_MODEL * 4 * D_MODEL * 2); // 16MB
  bf16* WoT   = (bf16*)alloc((size_t)D_MODEL * D_MODEL * 2);         // 2MB
  float* bkv  = (float*)alloc((size_t)2048 * 4);                     // 8KB
  bf16* q     = (bf16*)alloc((size_t)NTOK * D_MODEL * 2);            // 32MB (reused as attn-out)
  bf16* kv    = (bf16*)alloc((size_t)MTOK * 2048 * 2);               // 16MB (K | V, ldc=2048)
  bf16* vT    = (bf16*)alloc((size_t)MTOK * D_MODEL * 2);            // 8MB
  float* sc   = (float*)alloc((size_t)NTOK * 1024 * 4);              // 64MB
  bf16* attn  = (bf16*)alloc((size_t)NTOK * 1024 * 2);               // 32MB
  bf16* aout  = q;  // q dead after scores GEMM

  // 1) LayerNorm -> bf16
  ln_kernel<<<NTOK, 256, 0, stream>>>(x, ln_g, ln_b, xn);

  // 2) weight convert+transpose to (N,K) bf16 ; pack [bk;bv]
  transpose_to_bf16<float><<<dim3(32, 32, 1), dim3(32, 8), 0, stream>>>(Wq, WqT, 1024, 1024, 0, 0);
  transpose_to_bf16<float><<<dim3(32, 128, 1), dim3(32, 8), 0, stream>>>(Wk, WkvT, 1024, 4096, 0, 0);
  transpose_to_bf16<float><<<dim3(32, 128, 1), dim3(32, 8), 0, stream>>>(
      Wv, WkvT + (size_t)1024 * 4096, 1024, 4096, 0, 0);
  transpose_to_bf16<float><<<dim3(32, 32, 1), dim3(32, 8), 0, stream>>>(Wo, WoT, 1024, 1024, 0, 0);
  pack2<<<8, 256, 0, stream>>>(bk, bv, bkv);

  // 3) Q = xn @ Wq + bq    (16384,1024) K=1024, grid 256
  gemm8p<bf16, true, 8><<<dim3(4, 64, 1), 512, 0, stream>>>(
      xn, WqT, q, bq, 1.f, 1024, 1024, 1024, 1024, 0, 0, 0);

  // 4) [K|V] = xr @ [Wk|Wv] + [bk|bv]   (4096,2048) K=4096, BM=128 -> grid 256
  gemm8p<bf16, true, 4><<<dim3(8, 32, 1), 512, 0, stream>>>(
      xn, WkvT, kv, bkv, 1.f, 4096, 4096, 4096, 2048, 0, 0, 0);

  // 5) vT per batch: (1024 x 1024)@2048 -> transposed @1024
  transpose_to_bf16<bf16><<<dim3(32, 32, BATCH), dim3(32, 8), 0, stream>>>(
      kv + 1024, vT, 2048, 1024, (size_t)1024 * 2048, (size_t)1024 * 1024);

  // 6) scores = (q @ k^T)/32   batched fp32, grid 256
  gemm8p<float, false, 8><<<dim3(4, 16, 4), 512, 0, stream>>>(
      q, kv, sc, nullptr, 0.03125f, 1024, 1024, 2048, 1024,
      (size_t)4096 * 1024, (size_t)1024 * 2048, (size_t)4096 * 1024);

  // 7) softmax -> bf16
  softmax_kernel<<<NTOK, 256, 0, stream>>>(sc, attn);

  // 8) attn @ v   batched bf16 (into q's buffer), grid 256
  gemm8p<bf16, false, 8><<<dim3(4, 16, 4), 512, 0, stream>>>(
      attn, vT, aout, nullptr, 1.f, 1024, 1024, 1024, 1024,
      (size_t)4096 * 1024, (size_t)1024 * 1024, (size_t)4096 * 1024);

  // 9) out = aout @ Wo + bo   fp32, grid 256
  gemm8p<float, true, 8><<<dim3(4, 64, 1), 512, 0, stream>>>(
      aout, WoT, out, bo, 1.f, 1024, 1024, 1024, 1024, 0, 0, 0);
}